// Round 5
// baseline (280.912 us; speedup 1.0000x reference)
//
#include <hip/hip_runtime.h>
#include <hip/hip_bf16.h>

#define N_INS 16384
#define N_ATT 8192
#define KDIM  64
#define NCLU  64

typedef __attribute__((ext_vector_type(8))) short bf16x8;
typedef __attribute__((ext_vector_type(4))) float f32x4;

// ws layout (bytes):
// 0:  double Uu ; 8: double Vv        (zeroed)
// 64:    float Aseg[64*64]            (zeroed)
// 16448: float Bseg[64*64]            (zeroed)
// [0, 32832) zeroed each launch = 8208 floats
// 32832: float Gpart[2048]            (fully overwritten by k_heavy)
// 41024: float colpart_r[128*64]      (fully overwritten)
// 73792: float colpart_c[64*64]       (fully overwritten)
// 90176: bf16 Ucb[8192*64]  (1 MiB)  — TILED+SWIZZLED layout, see k_prep
#define OFF_ASEG   64
#define OFF_BSEG   16448
#define OFF_GPART  32832
#define OFF_CPR    41024
#define OFF_CPC    73792
#define OFF_UCB    90176
#define ZERO_FLOATS 8208

__device__ __forceinline__ unsigned short f2bf(float x) {
    unsigned u = __float_as_uint(x);
    u = (u + 0x7FFFu + ((u >> 16) & 1u)) >> 16;   // RNE
    return (unsigned short)u;
}

__device__ __forceinline__ float wave_red(float v) {
#pragma unroll
    for (int o = 32; o > 0; o >>= 1) v += __shfl_down(v, o, 64);
    return v;
}

// async 16B global -> LDS DMA (dest = wave-uniform base + lane*16)
typedef __attribute__((address_space(3))) unsigned int as3_u32;
typedef const __attribute__((address_space(1))) unsigned int as1_u32;
__device__ __forceinline__ void stage16(void* l, const void* g) {
    __builtin_amdgcn_global_load_lds((as1_u32*)g, (as3_u32*)l, 16, 0, 0);
}

// ---- prep: zero accum region, convert Uc->bf16 (tiled+swizzled), colsum partials ----
// Ucb layout: tile t = row>>4 (2KB each, 16 rows); within tile, row m = row&15 at
// m*128B; chunk q (8 bf16 = 16B, cols q*8..q*8+7) stored at ((q+m)&7)*16B.
// The rotation makes k_heavy's ds_read_b128 fragment reads bank-balanced (8/bank)
// while keeping the tile a contiguous 2KB block for linear global_load_lds staging.
// blocks [0,128):   zero + convert
// blocks [128,256): Ur colsum partials (128 rows each) -> colpart_r (plain stores)
// blocks [256,320): Uc colsum partials (128 rows each) -> colpart_c (plain stores)
__global__ void k_prep(const float* __restrict__ Ur, const float* __restrict__ Uc,
                       float* __restrict__ wsf,
                       float* __restrict__ cpr, float* __restrict__ cpc,
                       unsigned short* __restrict__ Ucb) {
    int blk = blockIdx.x, tid = threadIdx.x;
    if (blk < 128) {
        int gid = blk * 256 + tid;
        if (gid < ZERO_FLOATS) wsf[gid] = 0.0f;
        for (int c = gid; c < N_ATT * 8; c += 32768) {   // 65536 chunks, 2/thread
            int r = c >> 3, q = c & 7;
            const float4* src = (const float4*)(Uc + (size_t)r * 64 + q * 8);
            float4 x0 = src[0], x1 = src[1];
            uint4 v;
            v.x = (unsigned)f2bf(x0.x) | ((unsigned)f2bf(x0.y) << 16);
            v.y = (unsigned)f2bf(x0.z) | ((unsigned)f2bf(x0.w) << 16);
            v.z = (unsigned)f2bf(x1.x) | ((unsigned)f2bf(x1.y) << 16);
            v.w = (unsigned)f2bf(x1.z) | ((unsigned)f2bf(x1.w) << 16);
            int mrow = r & 15, t = r >> 4;
            size_t off_b = (size_t)t * 2048 + mrow * 128 + (((q + mrow) & 7) << 4);
            *(uint4*)((unsigned char*)Ucb + off_b) = v;
        }
        return;
    }
    __shared__ float cs2[256];
    bool isUr = blk < 256;
    int b = isUr ? (blk - 128) : (blk - 256);
    const float* base = (isUr ? Ur : Uc) + (size_t)b * 128 * KDIM;
    float* dst = (isUr ? cpr : cpc) + b * 64;
    int col = tid & 63, r0 = tid >> 6;
    float s = 0.f;
    for (int r = r0; r < 128; r += 4) s += base[r * KDIM + col];
    cs2[tid] = s;
    __syncthreads();
    if (tid < 64) dst[tid] = cs2[tid] + cs2[tid + 64] + cs2[tid + 128] + cs2[tid + 192];
}

// ---- per-row pass: argmax -> segment sums, and Sum u*log2(u) ----
// blocks [0,64): Ur rows (weights=bcol from colpart_c), 256 rows each
// blocks [64,96): Uc rows (weights=acol from colpart_r), 256 rows each
__global__ void k_pass(const float* __restrict__ Ur, const float* __restrict__ Uc,
                       const float* __restrict__ cpr, const float* __restrict__ cpc,
                       float* __restrict__ Aseg, float* __restrict__ Bseg,
                       double* __restrict__ accums) {
    __shared__ float wv[64];
    __shared__ float Part[64 * 65];   // +1 pad breaks bank aliasing
    __shared__ float psum[4];
    int blk = blockIdx.x, tid = threadIdx.x;
    bool isUr = blk < 64;
    const float* M = isUr ? Ur : Uc;
    float* Seg = isUr ? Aseg : Bseg;
    double* acc = isUr ? (accums + 0) : (accums + 1);
    int base_row = (isUr ? blk : blk - 64) * 256;

    if (tid < 64) {
        const float* cp = isUr ? cpc : cpr;
        int nb = isUr ? 64 : 128;
        float s = 0.f;
        for (int p = 0; p < nb; ++p) s += cp[p * 64 + tid];
        wv[tid] = s;
    }
    for (int i = tid; i < 64 * 65; i += 256) Part[i] = 0.f;
    __syncthreads();

    int row = base_row + tid;
    const float* rp = M + (size_t)row * KDIM;
    float best = -1e30f; int bidx = 0; float u = 0.f;
#pragma unroll
    for (int k = 0; k < 64; k += 4) {
        float4 v = *(const float4*)(rp + k);
        if (v.x > best) { best = v.x; bidx = k; }
        if (v.y > best) { best = v.y; bidx = k + 1; }
        if (v.z > best) { best = v.z; bidx = k + 2; }
        if (v.w > best) { best = v.w; bidx = k + 3; }
        u += v.x * wv[k] + v.y * wv[k + 1] + v.z * wv[k + 2] + v.w * wv[k + 3];
    }
    float p = u * __log2f(u);
    float pw = wave_red(p);
    if ((tid & 63) == 0) psum[tid >> 6] = pw;

    float* prow = &Part[bidx * 65];
#pragma unroll
    for (int k = 0; k < 64; k += 4) {
        float4 v = *(const float4*)(rp + k);
        atomicAdd(&prow[k],     v.x);
        atomicAdd(&prow[k + 1], v.y);
        atomicAdd(&prow[k + 2], v.z);
        atomicAdd(&prow[k + 3], v.w);
    }
    __syncthreads();
    if (tid == 0)
        atomicAdd(acc, (double)(psum[0] + psum[1] + psum[2] + psum[3]));
    for (int i = tid; i < 4096; i += 256)
        atomicAdd(&Seg[i], Part[(i >> 6) * 65 + (i & 63)]);
}

// ---- heavy: G = sum_ij d_ij * log2(d_ij) via bf16 MFMA, async-LDS pipeline ----
// grid 2048: rb = blk & 127 (128 rows), cc = blk >> 7 (512 cols = 32 tiles of 16)
// B tiles staged once per block via global_load_lds (waves 0/1), double-buffered;
// R4 had each wave redundantly global-loading the same tile (4x traffic, ~2000cyc
// dependent chains, VALUBusy 27%). Fragments via ds_read_b128 from the swizzled
// tile (8/bank balanced). No min-waves hint (R2: forcing 8/EU spilled).
__launch_bounds__(256)
__global__ void k_heavy(const float* __restrict__ Ur,
                        const unsigned short* __restrict__ Ucb,
                        float* __restrict__ Gpart) {
    __shared__ __align__(16) unsigned char bufs[2][2048];
    __shared__ float gsh[4];
    int tid = threadIdx.x;
    int wvi = tid >> 6, lane = tid & 63;
    int quad = lane >> 4, m = lane & 15;
    int rb = blockIdx.x & 127, cc = blockIdx.x >> 7;
    int row0 = rb * 128 + wvi * 32;

    // A fragments: A[m=lane&15][k=quad*8+j] from Ur rows, converted f32->bf16
    bf16x8 a[2][2];
#pragma unroll
    for (int t = 0; t < 2; ++t) {
        int ridx = row0 + t * 16 + m;
        const float* rp = Ur + (size_t)ridx * 64 + quad * 8;
#pragma unroll
        for (int h = 0; h < 2; ++h) {
            const float* rph = rp + h * 32;
            float4 x0 = *(const float4*)rph;
            float4 x1 = *(const float4*)(rph + 4);
            bf16x8 f;
            f[0] = (short)f2bf(x0.x); f[1] = (short)f2bf(x0.y);
            f[2] = (short)f2bf(x0.z); f[3] = (short)f2bf(x0.w);
            f[4] = (short)f2bf(x1.x); f[5] = (short)f2bf(x1.y);
            f[6] = (short)f2bf(x1.z); f[7] = (short)f2bf(x1.w);
            a[t][h] = f;
        }
    }

    // 32 tiles of 2KB each for this cc slice
    const unsigned char* gB = (const unsigned char*)Ucb + (size_t)(cc * 32) * 2048;
    if (wvi < 2)
        stage16(&bufs[0][wvi * 1024], gB + wvi * 1024 + lane * 16);

    // swizzled fragment offsets (chunk q of row m lives at ((q+m)&7)*16)
    int off0 = m * 128 + (((quad + m) & 7) << 4);
    int off1 = m * 128 + (((quad + 4 + m) & 7) << 4);

    float g = 0.f;
    for (int ct = 0; ct < 32; ++ct) {
        __syncthreads();   // staging wave drains vmcnt here -> tile ct visible
        if (ct + 1 < 32 && wvi < 2)
            stage16(&bufs[(ct + 1) & 1][wvi * 1024],
                    gB + (size_t)(ct + 1) * 2048 + wvi * 1024 + lane * 16);
        const unsigned char* bb = &bufs[ct & 1][0];
        bf16x8 b0 = *(const bf16x8*)(bb + off0);
        bf16x8 b1 = *(const bf16x8*)(bb + off1);
        f32x4 acc0 = {0.f, 0.f, 0.f, 0.f};
        f32x4 acc1 = {0.f, 0.f, 0.f, 0.f};
        acc0 = __builtin_amdgcn_mfma_f32_16x16x32_bf16(a[0][0], b0, acc0, 0, 0, 0);
        acc0 = __builtin_amdgcn_mfma_f32_16x16x32_bf16(a[0][1], b1, acc0, 0, 0, 0);
        acc1 = __builtin_amdgcn_mfma_f32_16x16x32_bf16(a[1][0], b0, acc1, 0, 0, 0);
        acc1 = __builtin_amdgcn_mfma_f32_16x16x32_bf16(a[1][1], b1, acc1, 0, 0, 0);
        // sum f(d) over tile elems is permutation-invariant -> C/D layout irrelevant
        // d ~ 16, eps*S ~ 2e-6: dropping +eps*S perturbs mi_org ~2e-7 << threshold
#pragma unroll
        for (int e = 0; e < 4; ++e) {
            float d0 = acc0[e]; g += d0 * __log2f(d0);
            float d1 = acc1[e]; g += d1 * __log2f(d1);
        }
    }
    float gw = wave_red(g);
    if (lane == 0) gsh[wvi] = gw;
    __syncthreads();
    if (tid == 0) Gpart[blockIdx.x] = gsh[0] + gsh[1] + gsh[2] + gsh[3];
}

// ---- final: S + G from partials, reduced-table MI (64x64), assemble loss ----
__global__ void k_final(const float* __restrict__ Aseg, const float* __restrict__ Bseg,
                        const float* __restrict__ cpr, const float* __restrict__ cpc,
                        const float* __restrict__ Gpart,
                        const double* __restrict__ accums, float* __restrict__ out) {
    __shared__ double Trr[4096];
    __shared__ double Prx[64], Pry[64];
    __shared__ double red[256];
    __shared__ double Ssh, Gsh;
    int tid = threadIdx.x;
    // S = (sum_b cpr) . (sum_b cpc)
    if (tid < 64) {
        double sa = 0.0, sb = 0.0;
        for (int p = 0; p < 128; ++p) sa += (double)cpr[p * 64 + tid];
        for (int p = 0; p < 64; ++p)  sb += (double)cpc[p * 64 + tid];
        red[tid] = sa * sb;
    }
    __syncthreads();
    if (tid == 0) {
        double s = 0.0;
        for (int k = 0; k < 64; ++k) s += red[k];
        Ssh = s;
    }
    __syncthreads();
    // G = sum Gpart
    {
        double gp = 0.0;
        for (int i = tid; i < 2048; i += 256) gp += (double)Gpart[i];
        red[tid] = gp;
    }
    __syncthreads();
    for (int s2 = 128; s2 > 0; s2 >>= 1) {
        if (tid < s2) red[tid] += red[tid + s2];
        __syncthreads();
    }
    if (tid == 0) Gsh = red[0];
    __syncthreads();
    double S = Ssh;
    int p = tid >> 2, qb = (tid & 3) * 16;
    for (int q = qb; q < qb + 16; ++q) {
        double s = 0.0;
        for (int k = 0; k < 64; ++k)
            s += (double)Aseg[p * 64 + k] * (double)Bseg[q * 64 + k];
        Trr[p * 64 + q] = s / S;
    }
    __syncthreads();
    if (tid < 64) {
        double s = 0.0;
        for (int q = 0; q < 64; ++q) s += Trr[tid * 64 + q];
        Prx[tid] = s;
    } else if (tid < 128) {
        int q = tid - 64;
        double s = 0.0;
        for (int pp = 0; pp < 64; ++pp) s += Trr[pp * 64 + q];
        Pry[q] = s;
    }
    __syncthreads();
    const double EPSd = 1e-15;
    double part = 0.0;
    for (int i = tid; i < 4096; i += 256) {
        double t = Trr[i];
        double txy = Prx[i >> 6] * Pry[i & 63];
        part += t * log((t + EPSd) / (txy + EPSd));
    }
    red[tid] = part;
    __syncthreads();
    for (int s2 = 128; s2 > 0; s2 >>= 1) {
        if (tid < s2) red[tid] += red[tid + s2];
        __syncthreads();
    }
    if (tid == 0) {
        const double inv_ln2 = 1.4426950408889634;
        double mi_red = red[0] * inv_ln2;
        double G = Gsh, Uu = accums[0], Vv = accums[1];
        double log2S = log(S) * inv_ln2;
        // mi_org = G/S + log2S - (Uu+Vv)/S
        double mi_org = G / S + log2S - (Uu + Vv) / S;
        double loss = log(1.0 + fabs(1.0 - mi_red / mi_org));
        out[0] = (float)loss;
    }
}

extern "C" void kernel_launch(void* const* d_in, const int* in_sizes, int n_in,
                              void* d_out, int out_size, void* d_ws, size_t ws_size,
                              hipStream_t stream) {
    const float* Ur = (const float*)d_in[0];
    const float* Uc = (const float*)d_in[1];
    float* out = (float*)d_out;
    char* ws = (char*)d_ws;
    double* accums = (double*)ws;
    float* Aseg  = (float*)(ws + OFF_ASEG);
    float* Bseg  = (float*)(ws + OFF_BSEG);
    float* Gpart = (float*)(ws + OFF_GPART);
    float* cpr   = (float*)(ws + OFF_CPR);
    float* cpc   = (float*)(ws + OFF_CPC);
    unsigned short* Ucb = (unsigned short*)(ws + OFF_UCB);

    k_prep<<<320, 256, 0, stream>>>(Ur, Uc, (float*)ws, cpr, cpc, Ucb);
    k_pass<<<96, 256, 0, stream>>>(Ur, Uc, cpr, cpc, Aseg, Bseg, accums);
    k_heavy<<<2048, 256, 0, stream>>>(Ur, Ucb, Gpart);
    k_final<<<1, 256, 0, stream>>>(Aseg, Bseg, cpr, cpc, Gpart, accums, out);
}

// Round 6
// 219.788 us; speedup vs baseline: 1.2781x; 1.2781x over previous
//
#include <hip/hip_runtime.h>
#include <hip/hip_bf16.h>

#define N_INS 16384
#define N_ATT 8192
#define KDIM  64
#define NCLU  64

typedef __attribute__((ext_vector_type(8))) short bf16x8;
typedef __attribute__((ext_vector_type(4))) float f32x4;

// ws layout (bytes):
// 0:  double Uu ; 8: double Vv        (zeroed)
// 64:    float Aseg[64*64]            (zeroed)
// 16448: float Bseg[64*64]            (zeroed)
// [0, 32832) zeroed each launch = 8208 floats
// 32832: float Gpart[2048]            (fully overwritten by k_heavy)
// 41024: float colpart_r[128*64]      (fully overwritten)
// 73792: float colpart_c[64*64]       (fully overwritten)
// 90176: bf16 Ucb[8192*64]  (1 MiB)  — FRAGMENT-ORDER tiles, see k_prep
#define OFF_ASEG   64
#define OFF_BSEG   16448
#define OFF_GPART  32832
#define OFF_CPR    41024
#define OFF_CPC    73792
#define OFF_UCB    90176
#define ZERO_FLOATS 8208

__device__ __forceinline__ unsigned short f2bf(float x) {
    unsigned u = __float_as_uint(x);
    u = (u + 0x7FFFu + ((u >> 16) & 1u)) >> 16;   // RNE
    return (unsigned short)u;
}

__device__ __forceinline__ float wave_red(float v) {
#pragma unroll
    for (int o = 32; o > 0; o >>= 1) v += __shfl_down(v, o, 64);
    return v;
}

// ---- prep: zero accum region, convert Uc->bf16 (fragment-order tiles), colsums ----
// Ucb layout: tile t = row>>4 (2KB, 16 rows). Lane ℓ=(quad*16+m) of a wave reads
// its b0 fragment (row m, k=quad*8..+7) at tile_base + ℓ*16 and b1 (k+32) at
// tile_base + 1024 + ℓ*16 — i.e. chunk q of row m at: q<4 ? q*256+m*16
// : 1024+(q-4)*256+m*16. Each wave B-load is one contiguous coalesced 1KB.
// blocks [0,128):   zero + convert
// blocks [128,256): Ur colsum partials (128 rows each) -> colpart_r (plain stores)
// blocks [256,320): Uc colsum partials (128 rows each) -> colpart_c (plain stores)
__global__ void k_prep(const float* __restrict__ Ur, const float* __restrict__ Uc,
                       float* __restrict__ wsf,
                       float* __restrict__ cpr, float* __restrict__ cpc,
                       unsigned short* __restrict__ Ucb) {
    int blk = blockIdx.x, tid = threadIdx.x;
    if (blk < 128) {
        int gid = blk * 256 + tid;
        if (gid < ZERO_FLOATS) wsf[gid] = 0.0f;
        for (int c = gid; c < N_ATT * 8; c += 32768) {   // 65536 chunks, 2/thread
            int r = c >> 3, q = c & 7;
            const float4* src = (const float4*)(Uc + (size_t)r * 64 + q * 8);
            float4 x0 = src[0], x1 = src[1];
            uint4 v;
            v.x = (unsigned)f2bf(x0.x) | ((unsigned)f2bf(x0.y) << 16);
            v.y = (unsigned)f2bf(x0.z) | ((unsigned)f2bf(x0.w) << 16);
            v.z = (unsigned)f2bf(x1.x) | ((unsigned)f2bf(x1.y) << 16);
            v.w = (unsigned)f2bf(x1.z) | ((unsigned)f2bf(x1.w) << 16);
            int m = r & 15, t = r >> 4;
            int woff = (q < 4) ? (q * 256 + m * 16) : (1024 + (q - 4) * 256 + m * 16);
            *(uint4*)((unsigned char*)Ucb + (size_t)t * 2048 + woff) = v;
        }
        return;
    }
    __shared__ float cs2[256];
    bool isUr = blk < 256;
    int b = isUr ? (blk - 128) : (blk - 256);
    const float* base = (isUr ? Ur : Uc) + (size_t)b * 128 * KDIM;
    float* dst = (isUr ? cpr : cpc) + b * 64;
    int col = tid & 63, r0 = tid >> 6;
    float s = 0.f;
    for (int r = r0; r < 128; r += 4) s += base[r * KDIM + col];
    cs2[tid] = s;
    __syncthreads();
    if (tid < 64) dst[tid] = cs2[tid] + cs2[tid + 64] + cs2[tid + 128] + cs2[tid + 192];
}

// ---- per-row pass: argmax -> segment sums, and Sum u*log2(u) ----
__global__ void k_pass(const float* __restrict__ Ur, const float* __restrict__ Uc,
                       const float* __restrict__ cpr, const float* __restrict__ cpc,
                       float* __restrict__ Aseg, float* __restrict__ Bseg,
                       double* __restrict__ accums) {
    __shared__ float wv[64];
    __shared__ float Part[64 * 65];   // +1 pad breaks bank aliasing
    __shared__ float psum[4];
    int blk = blockIdx.x, tid = threadIdx.x;
    bool isUr = blk < 64;
    const float* M = isUr ? Ur : Uc;
    float* Seg = isUr ? Aseg : Bseg;
    double* acc = isUr ? (accums + 0) : (accums + 1);
    int base_row = (isUr ? blk : blk - 64) * 256;

    if (tid < 64) {
        const float* cp = isUr ? cpc : cpr;
        int nb = isUr ? 64 : 128;
        float s = 0.f;
        for (int p = 0; p < nb; ++p) s += cp[p * 64 + tid];
        wv[tid] = s;
    }
    for (int i = tid; i < 64 * 65; i += 256) Part[i] = 0.f;
    __syncthreads();

    int row = base_row + tid;
    const float* rp = M + (size_t)row * KDIM;
    float best = -1e30f; int bidx = 0; float u = 0.f;
#pragma unroll
    for (int k = 0; k < 64; k += 4) {
        float4 v = *(const float4*)(rp + k);
        if (v.x > best) { best = v.x; bidx = k; }
        if (v.y > best) { best = v.y; bidx = k + 1; }
        if (v.z > best) { best = v.z; bidx = k + 2; }
        if (v.w > best) { best = v.w; bidx = k + 3; }
        u += v.x * wv[k] + v.y * wv[k + 1] + v.z * wv[k + 2] + v.w * wv[k + 3];
    }
    float p = u * __log2f(u);
    float pw = wave_red(p);
    if ((tid & 63) == 0) psum[tid >> 6] = pw;

    float* prow = &Part[bidx * 65];
#pragma unroll
    for (int k = 0; k < 64; k += 4) {
        float4 v = *(const float4*)(rp + k);
        atomicAdd(&prow[k],     v.x);
        atomicAdd(&prow[k + 1], v.y);
        atomicAdd(&prow[k + 2], v.z);
        atomicAdd(&prow[k + 3], v.w);
    }
    __syncthreads();
    if (tid == 0)
        atomicAdd(acc, (double)(psum[0] + psum[1] + psum[2] + psum[3]));
    for (int i = tid; i < 4096; i += 256)
        atomicAdd(&Seg[i], Part[(i >> 6) * 65 + (i & 63)]);
}

// ---- heavy: G = sum_ij d_ij * log2(d_ij), bf16 MFMA + register-pipelined B ----
// grid 2048: rb = blk & 127 (128 rows), cc = blk >> 7 (512 cols = 16 tile-PAIRS)
// R4 stall: per-tile dependent load->mfma chain (~250cyc) vs ~130cyc work,
// VALUBusy 27%. Fix: 2 tiles/iter (8 MFMAs, 16-log epilogue ~200cyc) + prefetch
// next pair into REGISTERS during current pair's compute. No LDS staging (R5:
// compiler blew up to 244 VGPR). #pragma unroll 1 pins the loop shape.
__launch_bounds__(256)
__global__ void k_heavy(const float* __restrict__ Ur,
                        const unsigned char* __restrict__ Ucb,
                        float* __restrict__ Gpart) {
    __shared__ float gsh[4];
    int tid = threadIdx.x;
    int wvi = tid >> 6, lane = tid & 63;
    int quad = lane >> 4, m = lane & 15;
    int rb = blockIdx.x & 127, cc = blockIdx.x >> 7;
    int row0 = rb * 128 + wvi * 32;

    // A fragments: A[m=lane&15][k=quad*8+j] from Ur rows, converted f32->bf16
    bf16x8 a[2][2];
#pragma unroll
    for (int t = 0; t < 2; ++t) {
        int ridx = row0 + t * 16 + m;
        const float* rp = Ur + (size_t)ridx * 64 + quad * 8;
#pragma unroll
        for (int h = 0; h < 2; ++h) {
            const float* rph = rp + h * 32;
            float4 x0 = *(const float4*)rph;
            float4 x1 = *(const float4*)(rph + 4);
            bf16x8 f;
            f[0] = (short)f2bf(x0.x); f[1] = (short)f2bf(x0.y);
            f[2] = (short)f2bf(x0.z); f[3] = (short)f2bf(x0.w);
            f[4] = (short)f2bf(x1.x); f[5] = (short)f2bf(x1.y);
            f[6] = (short)f2bf(x1.z); f[7] = (short)f2bf(x1.w);
            a[t][h] = f;
        }
    }

    // 32 tiles (16 pairs) of 2KB; lane's fragment bytes at tile_base + lane*16
    const unsigned char* gB = Ucb + (size_t)(cc * 32) * 2048 + lane * 16;
    bf16x8 c00 = *(const bf16x8*)(gB);
    bf16x8 c01 = *(const bf16x8*)(gB + 1024);
    bf16x8 c10 = *(const bf16x8*)(gB + 2048);
    bf16x8 c11 = *(const bf16x8*)(gB + 3072);

    float g = 0.f;
#pragma unroll 1
    for (int pt = 0; pt < 16; ++pt) {
        int npt = (pt < 15) ? (pt + 1) : 15;       // clamped: branchless, in-bounds
        const unsigned char* nb = gB + (size_t)npt * 4096;
        bf16x8 n00 = *(const bf16x8*)(nb);
        bf16x8 n01 = *(const bf16x8*)(nb + 1024);
        bf16x8 n10 = *(const bf16x8*)(nb + 2048);
        bf16x8 n11 = *(const bf16x8*)(nb + 3072);

        f32x4 acc00 = {0.f, 0.f, 0.f, 0.f};
        f32x4 acc01 = {0.f, 0.f, 0.f, 0.f};
        f32x4 acc10 = {0.f, 0.f, 0.f, 0.f};
        f32x4 acc11 = {0.f, 0.f, 0.f, 0.f};
        acc00 = __builtin_amdgcn_mfma_f32_16x16x32_bf16(a[0][0], c00, acc00, 0, 0, 0);
        acc00 = __builtin_amdgcn_mfma_f32_16x16x32_bf16(a[0][1], c01, acc00, 0, 0, 0);
        acc10 = __builtin_amdgcn_mfma_f32_16x16x32_bf16(a[1][0], c00, acc10, 0, 0, 0);
        acc10 = __builtin_amdgcn_mfma_f32_16x16x32_bf16(a[1][1], c01, acc10, 0, 0, 0);
        acc01 = __builtin_amdgcn_mfma_f32_16x16x32_bf16(a[0][0], c10, acc01, 0, 0, 0);
        acc01 = __builtin_amdgcn_mfma_f32_16x16x32_bf16(a[0][1], c11, acc01, 0, 0, 0);
        acc11 = __builtin_amdgcn_mfma_f32_16x16x32_bf16(a[1][0], c10, acc11, 0, 0, 0);
        acc11 = __builtin_amdgcn_mfma_f32_16x16x32_bf16(a[1][1], c11, acc11, 0, 0, 0);
        // sum f(d) over tile elems is permutation-invariant -> C/D layout irrelevant
        // d ~ 16, eps*S ~ 2e-6: dropping +eps*S perturbs mi_org ~2e-7 << threshold
#pragma unroll
        for (int e = 0; e < 4; ++e) {
            float d0 = acc00[e]; g += d0 * __log2f(d0);
            float d1 = acc01[e]; g += d1 * __log2f(d1);
            float d2 = acc10[e]; g += d2 * __log2f(d2);
            float d3 = acc11[e]; g += d3 * __log2f(d3);
        }
        c00 = n00; c01 = n01; c10 = n10; c11 = n11;
    }
    float gw = wave_red(g);
    if (lane == 0) gsh[wvi] = gw;
    __syncthreads();
    if (tid == 0) Gpart[blockIdx.x] = gsh[0] + gsh[1] + gsh[2] + gsh[3];
}

// ---- final: S + G from partials, reduced-table MI (64x64), assemble loss ----
__global__ void k_final(const float* __restrict__ Aseg, const float* __restrict__ Bseg,
                        const float* __restrict__ cpr, const float* __restrict__ cpc,
                        const float* __restrict__ Gpart,
                        const double* __restrict__ accums, float* __restrict__ out) {
    __shared__ double Trr[4096];
    __shared__ double Prx[64], Pry[64];
    __shared__ double red[256];
    __shared__ double Ssh, Gsh;
    int tid = threadIdx.x;
    // S = (sum_b cpr) . (sum_b cpc)
    if (tid < 64) {
        double sa = 0.0, sb = 0.0;
        for (int p = 0; p < 128; ++p) sa += (double)cpr[p * 64 + tid];
        for (int p = 0; p < 64; ++p)  sb += (double)cpc[p * 64 + tid];
        red[tid] = sa * sb;
    }
    __syncthreads();
    if (tid == 0) {
        double s = 0.0;
        for (int k = 0; k < 64; ++k) s += red[k];
        Ssh = s;
    }
    __syncthreads();
    // G = sum Gpart
    {
        double gp = 0.0;
        for (int i = tid; i < 2048; i += 256) gp += (double)Gpart[i];
        red[tid] = gp;
    }
    __syncthreads();
    for (int s2 = 128; s2 > 0; s2 >>= 1) {
        if (tid < s2) red[tid] += red[tid + s2];
        __syncthreads();
    }
    if (tid == 0) Gsh = red[0];
    __syncthreads();
    double S = Ssh;
    int p = tid >> 2, qb = (tid & 3) * 16;
    for (int q = qb; q < qb + 16; ++q) {
        double s = 0.0;
        for (int k = 0; k < 64; ++k)
            s += (double)Aseg[p * 64 + k] * (double)Bseg[q * 64 + k];
        Trr[p * 64 + q] = s / S;
    }
    __syncthreads();
    if (tid < 64) {
        double s = 0.0;
        for (int q = 0; q < 64; ++q) s += Trr[tid * 64 + q];
        Prx[tid] = s;
    } else if (tid < 128) {
        int q = tid - 64;
        double s = 0.0;
        for (int pp = 0; pp < 64; ++pp) s += Trr[pp * 64 + q];
        Pry[q] = s;
    }
    __syncthreads();
    const double EPSd = 1e-15;
    double part = 0.0;
    for (int i = tid; i < 4096; i += 256) {
        double t = Trr[i];
        double txy = Prx[i >> 6] * Pry[i & 63];
        part += t * log((t + EPSd) / (txy + EPSd));
    }
    red[tid] = part;
    __syncthreads();
    for (int s2 = 128; s2 > 0; s2 >>= 1) {
        if (tid < s2) red[tid] += red[tid + s2];
        __syncthreads();
    }
    if (tid == 0) {
        const double inv_ln2 = 1.4426950408889634;
        double mi_red = red[0] * inv_ln2;
        double G = Gsh, Uu = accums[0], Vv = accums[1];
        double log2S = log(S) * inv_ln2;
        // mi_org = G/S + log2S - (Uu+Vv)/S
        double mi_org = G / S + log2S - (Uu + Vv) / S;
        double loss = log(1.0 + fabs(1.0 - mi_red / mi_org));
        out[0] = (float)loss;
    }
}

extern "C" void kernel_launch(void* const* d_in, const int* in_sizes, int n_in,
                              void* d_out, int out_size, void* d_ws, size_t ws_size,
                              hipStream_t stream) {
    const float* Ur = (const float*)d_in[0];
    const float* Uc = (const float*)d_in[1];
    float* out = (float*)d_out;
    char* ws = (char*)d_ws;
    double* accums = (double*)ws;
    float* Aseg  = (float*)(ws + OFF_ASEG);
    float* Bseg  = (float*)(ws + OFF_BSEG);
    float* Gpart = (float*)(ws + OFF_GPART);
    float* cpr   = (float*)(ws + OFF_CPR);
    float* cpc   = (float*)(ws + OFF_CPC);
    unsigned short* Ucb = (unsigned short*)(ws + OFF_UCB);

    k_prep<<<320, 256, 0, stream>>>(Ur, Uc, (float*)ws, cpr, cpc, Ucb);
    k_pass<<<96, 256, 0, stream>>>(Ur, Uc, cpr, cpc, Aseg, Bseg, accums);
    k_heavy<<<2048, 256, 0, stream>>>(Ur, (const unsigned char*)Ucb, Gpart);
    k_final<<<1, 256, 0, stream>>>(Aseg, Bseg, cpr, cpc, Gpart, accums, out);
}